// Round 7
// baseline (652.694 us; speedup 1.0000x reference)
//
#include <hip/hip_runtime.h>

// Problem constants (compile-time; from reference: T,B,N,R,E,D = 20,4,50000,4,1600000,5)
namespace {
constexpr int TS = 20;
constexpr int B  = 4;
constexpr int N  = 50000;
constexpr int R  = 4;
constexpr int E  = 1600000;
constexpr int D  = 5;
constexpr int NR = N * R;           // 200000
constexpr float DT = 1.0f;

typedef float f32x4 __attribute__((ext_vector_type(4)));

// Workspace layout (bytes). All offsets 16B-aligned.
// zpack occupies N*D = 250000 bytes; cnt (TS+D ints = 100B) lives in the pad.
constexpr size_t OFF_ZPACK = 0;
constexpr size_t OFF_CNT   = 250112;                              // 16B-aligned, inside 256K pad
constexpr size_t OFF_REC   = 262144;                              // B*N*R floats = 3,200,000 B
constexpr size_t OFF_RBUF  = OFF_REC  + (size_t)B * N * R * 4;    // B*N floats
constexpr size_t OFF_ASC1  = OFF_RBUF + (size_t)B * N * 4;
constexpr size_t OFF_ASC2  = OFF_ASC1 + (size_t)B * N * 4;
constexpr size_t OFF_PR    = OFF_ASC2 + (size_t)B * N * 4;        // psc_rise: B*N*R floats
constexpr size_t OFF_PC    = OFF_PR   + (size_t)B * N * R * 4;    // psc:      B*N*R floats
constexpr size_t OFF_V     = OFF_PC   + (size_t)B * N * R * 4;    // v:        B*N floats
constexpr size_t ZERO_BYTES = OFF_V;                              // zpack+cnt+rec+rbuf+asc+psc zero-init
// total ws use = OFF_V + 800000 = 13,062,144 bytes (~12.5 MB)
}

// v[b,n] = e_l[n]
__global__ __launch_bounds__(256) void vinit_kernel(float* __restrict__ v,
                                                    const float* __restrict__ e_l) {
  int i = blockIdx.x * 256 + threadIdx.x;
  if (i < B * N) v[i] = e_l[i % N];  // N compile-time -> magic-mul, no real div
}

// Phase 1: rec[b, rows[e]] += weights[e] * z_buf[b, cols[e]]
// z is binary; zpack holds a 4-bit batch mask per (delay_slot, neuron).
// Each thread handles 4 consecutive edges (int4 load of cols -> dwordx4).
// cnt_win[0..D-1] = spike counts of steps t-D..t-1; if all zero, the whole
// ring is silent and this dispatch is a no-op (early transient steps).
__global__ __launch_bounds__(256) void gather_kernel(const int4* __restrict__ cols4,
                                                     const int* __restrict__ rows,
                                                     const float* __restrict__ weights,
                                                     const unsigned char* __restrict__ zpack,
                                                     float* __restrict__ rec,
                                                     const int* __restrict__ cnt_win,
                                                     int head) {
  // wave-uniform early-out: 5 scalar loads, no per-edge work when ring silent
  int tot = cnt_win[0] + cnt_win[1] + cnt_win[2] + cnt_win[3] + cnt_win[4];
  if (tot == 0) return;

  int q = blockIdx.x * 256 + threadIdx.x;          // quad index, E/4 = 400000
  if (q >= E / 4) return;
  const int4 c4 = cols4[q];

#pragma unroll
  for (int j = 0; j < 4; ++j) {
    const int c = (j == 0) ? c4.x : (j == 1) ? c4.y : (j == 2) ? c4.z : c4.w;
    int d = c / N;               // compile-time N -> magic multiply
    int n = c - d * N;
    int slot = head + d; if (slot >= D) slot -= D; // ring: logical delay d -> physical slot
    const unsigned char m = zpack[slot * N + n];
    if (m) {
      const int e = q * 4 + j;
      const float w = weights[e];
      const int row = rows[e];
      if (m & 1) atomicAdd(rec + 0 * NR + row, w);
      if (m & 2) atomicAdd(rec + 1 * NR + row, w);
      if (m & 4) atomicAdd(rec + 2 * NR + row, w);
      if (m & 8) atomicAdd(rec + 3 * NR + row, w);
    }
  }
}

// Phase 2: dense per-neuron update. One thread per neuron n, loops over the 4 batches.
// Also zeroes rec for the next step, writes the new packed spike mask, and bumps
// this step's spike counter (wave-coalesced atomic).
__global__ __launch_bounds__(256) void neuron_kernel(
    const f32x4* __restrict__ x_t,         // B*N float4 (this timestep)
    const float4* __restrict__ syn_decay,  // N
    const float4* __restrict__ psc_init,   // N
    const float2* __restrict__ asc_amps,   // N
    const float* __restrict__ exp_k1, const float* __restrict__ exp_k2,
    const float* __restrict__ decay,  const float* __restrict__ cur_fac,
    const float* __restrict__ v_th,   const float* __restrict__ e_l,
    const float* __restrict__ v_reset,const float* __restrict__ t_ref,
    const float* __restrict__ param_g,
    float4* __restrict__ rec,              // B*N float4 (zeroed after read)
    float*  __restrict__ v,    float* __restrict__ rbuf,
    float*  __restrict__ asc1, float* __restrict__ asc2,
    float4* __restrict__ psc_rise, float4* __restrict__ psc,
    unsigned char* __restrict__ zpack,
    int* __restrict__ cnt_t,               // &cnt[t+D]
    int head, int newslot,
    float* __restrict__ out_t) {           // B*N (this timestep's spikes)
  int n = blockIdx.x * 256 + threadIdx.x;
  if (n >= N) return;

  const float4 sd  = syn_decay[n];
  const float4 pi  = psc_init[n];
  const float2 amp = asc_amps[n];
  const float k1n = exp_k1[n], k2n = exp_k2[n];
  const float dec = decay[n],  cfn = cur_fac[n];
  const float vth = v_th[n],   eln = e_l[n];
  const float vrs = v_reset[n], trf = t_ref[n], pg = param_g[n];
  const float norm = vth - eln;        // normalizer
  const float vgap = vrs - vth;        // v_gap
  const float gg   = pg * eln;         // gathered_g

  const unsigned char prevmask = zpack[head * N + n];
  unsigned char newmask = 0;

#pragma unroll
  for (int b = 0; b < B; ++b) {
    const int bn = b * N + n;
    float4 pr = psc_rise[bn];
    float4 pc = psc[bn];
    float4 rc = rec[bn];
    rec[bn] = make_float4(0.f, 0.f, 0.f, 0.f);     // ready for next step's atomics
    // x streamed exactly once over the whole problem -> keep it out of L2
    f32x4 xx = __builtin_nontemporal_load(x_t + bn);

    // inp = rec + x_t
    float ix = rc.x + xx.x, iy = rc.y + xx.y, iz = rc.z + xx.z, iw = rc.w + xx.w;
    // new_psc = sd*psc + DT*sd*psc_rise  (uses OLD psc_rise)
    float4 npc = { sd.x * pc.x + sd.x * pr.x,
                   sd.y * pc.y + sd.y * pr.y,
                   sd.z * pc.z + sd.z * pr.z,
                   sd.w * pc.w + sd.w * pr.w };
    // new_psc_rise = sd*psc_rise + psc_init*inp
    float4 npr = { sd.x * pr.x + pi.x * ix,
                   sd.y * pr.y + pi.y * iy,
                   sd.z * pr.z + pi.z * iz,
                   sd.w * pr.w + pi.w * iw };
    psc[bn] = npc;
    psc_rise[bn] = npr;

    const float I = npc.x + npc.y + npc.z + npc.w;
    const float pz = (prevmask >> b) & 1 ? 1.0f : 0.0f;

    float a1 = asc1[bn];
    float a2 = asc2[bn];
    const float c1 = I + a1 + a2 + gg;             // uses OLD asc1/asc2
    asc1[bn] = k1n * a1 + pz * amp.x;
    asc2[bn] = k2n * a2 + pz * amp.y;

    const float vo = v[bn];
    const float vn = dec * vo + cfn * c1 + pz * vgap;
    v[bn] = vn;

    const float vsc = (vn - vth) / norm;
    float z = (vsc > 0.f) ? 1.0f : 0.0f;
    const float rr = rbuf[bn];
    if (rr > 0.f) z = 0.0f;                        // refractory mask
    float rn = rr + z * trf - DT;
    rn = fminf(fmaxf(rn, 0.f), trf);               // clip(., 0, t_ref)
    rbuf[bn] = rn;

    // out written exactly once -> nontemporal store, don't evict state from L2
    __builtin_nontemporal_store(z, &out_t[bn]);
    newmask |= (unsigned char)((z != 0.f) ? (1 << b) : 0);
  }
  zpack[newslot * N + n] = newmask;
  if (newmask) atomicAdd(cnt_t, 1);                // compiler coalesces per-wave (G12)
}

extern "C" void kernel_launch(void* const* d_in, const int* in_sizes, int n_in,
                              void* d_out, int out_size, void* d_ws, size_t ws_size,
                              hipStream_t stream) {
  const float* x        = (const float*)d_in[0];   // (T,B,N,R)
  const float* weights  = (const float*)d_in[1];   // (E,)
  const float* syn_dec  = (const float*)d_in[2];   // (N,R)
  const float* psc_init = (const float*)d_in[3];   // (N,R)
  const float* asc_amps = (const float*)d_in[4];   // (N,2)
  const float* exp_k1   = (const float*)d_in[5];
  const float* exp_k2   = (const float*)d_in[6];
  const float* decay    = (const float*)d_in[7];
  const float* cur_fac  = (const float*)d_in[8];
  const float* v_th     = (const float*)d_in[9];
  const float* e_l      = (const float*)d_in[10];
  const float* v_reset  = (const float*)d_in[11];
  const float* t_ref    = (const float*)d_in[12];
  const float* param_g  = (const float*)d_in[13];
  // d_in[14] = dampening (backward-only, unused)
  const int* rows       = (const int*)d_in[15];
  const int* cols       = (const int*)d_in[16];

  char* ws = (char*)d_ws;
  unsigned char* zpack = (unsigned char*)(ws + OFF_ZPACK);
  int*   cnt   = (int*)(ws + OFF_CNT);             // TS+D entries, leading D are step<0 (zero)
  float* rec   = (float*)(ws + OFF_REC);
  float* rbuf  = (float*)(ws + OFF_RBUF);
  float* asc1  = (float*)(ws + OFF_ASC1);
  float* asc2  = (float*)(ws + OFF_ASC2);
  float* prise = (float*)(ws + OFF_PR);
  float* psc   = (float*)(ws + OFF_PC);
  float* v     = (float*)(ws + OFF_V);
  float* out   = (float*)d_out;

  // Zero-init all state (ws is poisoned 0xAA before every timed call).
  (void)hipMemsetAsync(ws, 0, ZERO_BYTES, stream);
  vinit_kernel<<<(B * N + 255) / 256, 256, 0, stream>>>(v, e_l);

  const int gather_blocks = (E / 4 + 255) / 256;   // 1563 (4 edges/thread)
  const int neuron_blocks = (N + 255) / 256;       // 196

  for (int t = 0; t < TS; ++t) {
    const int head    = (D - (t % D)) % D;         // slot holding the most recent z
    const int newslot = (head + D - 1) % D;        // where this step's z goes

    // cnt window: counts of steps t-1..t-D live at cnt[t+D-1]..cnt[t]
    gather_kernel<<<gather_blocks, 256, 0, stream>>>((const int4*)cols, rows, weights,
                                                     zpack, rec, cnt + t, head);

    neuron_kernel<<<neuron_blocks, 256, 0, stream>>>(
        (const f32x4*)(x + (size_t)t * B * N * R),
        (const float4*)syn_dec, (const float4*)psc_init, (const float2*)asc_amps,
        exp_k1, exp_k2, decay, cur_fac, v_th, e_l, v_reset, t_ref, param_g,
        (float4*)rec, v, rbuf, asc1, asc2,
        (float4*)prise, (float4*)psc,
        zpack, cnt + t + D, head, newslot,
        out + (size_t)t * B * N);
  }
}